// Round 1
// baseline (8834.609 us; speedup 1.0000x reference)
//
#include <hip/hip_runtime.h>

#define BB 4
#define LL 4096
#define CC 512
#define DKK 64
#define OUTC 512
#define MTOT (BB*LL)   // 16384

// ---------------- Kernel A: fused QKV projection ----------------
// y = x @ W^T + b for Wq(64xC), Wk(64xC), Wv(512xC) -> N = 640 cols total
// grid: (MTOT/64, 640/64) = (256, 10), block 256
__global__ __launch_bounds__(256) void qkv_proj(
    const float* __restrict__ x,
    const float* __restrict__ Wq, const float* __restrict__ bq,
    const float* __restrict__ Wk, const float* __restrict__ bk,
    const float* __restrict__ Wv, const float* __restrict__ bv,
    float* __restrict__ qout, float* __restrict__ kout, float* __restrict__ vout)
{
    __shared__ float xs[64][33];
    __shared__ float ws[64][33];
    const int m0 = blockIdx.x * 64;
    const int n0 = blockIdx.y * 64;

    // which weight matrix does this 64-wide column tile belong to?
    // n0==0 -> Wq, n0==64 -> Wk, n0>=128 -> Wv rows (n0-128)
    const int kind = (n0 == 0) ? 0 : (n0 == 64) ? 1 : 2;
    const float* Wsrc = (kind == 0) ? Wq : (kind == 1) ? Wk : Wv;
    const float* bsrc = (kind == 0) ? bq : (kind == 1) ? bk : bv;
    const int nloc0 = (kind == 2) ? (n0 - 128) : 0;

    const int tid = threadIdx.x;
    const int ty = tid >> 4;   // 0..15
    const int tx = tid & 15;   // 0..15

    float acc[4][4] = {};

    for (int kc = 0; kc < CC; kc += 32) {
        // x tile: 64 rows x 32 cols = 512 float4
        for (int s = tid; s < 512; s += 256) {
            const int r = s >> 3, c4 = s & 7;
            const float4 t = *(const float4*)&x[(size_t)(m0 + r) * CC + kc + c4 * 4];
            xs[r][c4 * 4 + 0] = t.x; xs[r][c4 * 4 + 1] = t.y;
            xs[r][c4 * 4 + 2] = t.z; xs[r][c4 * 4 + 3] = t.w;
        }
        // W tile: 64 rows x 32 cols
        for (int s = tid; s < 512; s += 256) {
            const int r = s >> 3, c4 = s & 7;
            const float4 t = *(const float4*)&Wsrc[(size_t)(nloc0 + r) * CC + kc + c4 * 4];
            ws[r][c4 * 4 + 0] = t.x; ws[r][c4 * 4 + 1] = t.y;
            ws[r][c4 * 4 + 2] = t.z; ws[r][c4 * 4 + 3] = t.w;
        }
        __syncthreads();
        #pragma unroll
        for (int kk = 0; kk < 32; ++kk) {
            float a[4], b[4];
            #pragma unroll
            for (int i = 0; i < 4; ++i) a[i] = xs[ty * 4 + i][kk];
            #pragma unroll
            for (int j = 0; j < 4; ++j) b[j] = ws[tx * 4 + j][kk];
            #pragma unroll
            for (int i = 0; i < 4; ++i)
                #pragma unroll
                for (int j = 0; j < 4; ++j)
                    acc[i][j] += a[i] * b[j];
        }
        __syncthreads();
    }

    #pragma unroll
    for (int i = 0; i < 4; ++i) {
        const int m = m0 + ty * 4 + i;
        #pragma unroll
        for (int j = 0; j < 4; ++j) {
            const int nl = nloc0 + tx * 4 + j;
            const float val = acc[i][j] + bsrc[nl];
            if (kind == 0)       qout[(size_t)m * DKK + nl] = val;
            else if (kind == 1)  kout[(size_t)m * DKK + nl] = val;
            else                 vout[(size_t)m * OUTC + nl] = val;
        }
    }
}

// ---------------- Kernel B: causal flash attention (fp32) ----------------
// One block per (batch, 32-row q tile). 256 threads:
//   thread -> (r = tid/8 in [0,32), tc = tid%8 -> 64-col chunk of OUT)
#define QT 32
#define KT 16

__global__ __launch_bounds__(256) void flash_attn(
    const float* __restrict__ q, const float* __restrict__ k,
    const float* __restrict__ v, float* __restrict__ out)
{
    __shared__ float qs[QT][DKK];        // 8 KB
    __shared__ float ks[KT][DKK];        // 4 KB
    __shared__ float vs[KT][OUTC];       // 32 KB
    __shared__ float sc[QT][KT + 1];     // scores, padded

    const int b  = blockIdx.y;
    const int q0 = blockIdx.x * QT;
    const int tid = threadIdx.x;
    const int r  = tid >> 3;   // row in q tile
    const int tc = tid & 7;    // 64-col chunk

    // load q tile (32x64 = 512 float4)
    const size_t qoff = ((size_t)b * LL + q0) * DKK;
    for (int s = tid; s < 512; s += 256) {
        const int rr = s >> 4, c4 = s & 15;
        *(float4*)&qs[rr][c4 * 4] = *(const float4*)&q[qoff + (size_t)rr * DKK + c4 * 4];
    }

    float o[64];
    #pragma unroll
    for (int i = 0; i < 64; ++i) o[i] = 0.f;
    float m_r = -1e30f, l_r = 0.f;

    const int ntiles = (q0 + QT) / KT;   // causal: only k0 <= q0+31
    for (int t = 0; t < ntiles; ++t) {
        const int k0 = t * KT;
        __syncthreads();   // previous iteration done consuming ks/vs
        // stage k tile (16x64 = 256 float4): one per thread
        {
            const int rr = tid >> 4, c4 = tid & 15;
            *(float4*)&ks[rr][c4 * 4] =
                *(const float4*)&k[((size_t)b * LL + k0 + rr) * DKK + c4 * 4];
        }
        // stage v tile (16x512 = 2048 float4): 8 per thread
        for (int s = tid; s < 2048; s += 256) {
            const int vr = s >> 7, vc4 = s & 127;
            *(float4*)&vs[vr][vc4 * 4] =
                *(const float4*)&v[((size_t)b * LL + k0 + vr) * OUTC + vc4 * 4];
        }
        __syncthreads();

        // scores: 32x16 = 512, 2 per thread
        {
            const int sq = tid >> 3;
            const int skb = (tid & 7) * 2;
            #pragma unroll
            for (int e = 0; e < 2; ++e) {
                const int sk = skb + e;
                float s = 0.f;
                #pragma unroll
                for (int d = 0; d < DKK; d += 4) {
                    const float4 qa = *(const float4*)&qs[sq][d];
                    const float4 kb = *(const float4*)&ks[sk][d];
                    s += qa.x * kb.x + qa.y * kb.y + qa.z * kb.z + qa.w * kb.w;
                }
                s *= 0.125f;
                if (k0 + sk > q0 + sq) s = -1e30f;   // causal mask
                sc[sq][sk] = s;
            }
        }
        __syncthreads();

        // online softmax + PV update; each thread handles its (r, tc) chunk
        float p[KT];
        float tm = -1e30f;
        #pragma unroll
        for (int kk = 0; kk < KT; ++kk) tm = fmaxf(tm, sc[r][kk]);
        const float nm = fmaxf(m_r, tm);
        const float corr = __expf(m_r - nm);
        float ts = 0.f;
        #pragma unroll
        for (int kk = 0; kk < KT; ++kk) { p[kk] = __expf(sc[r][kk] - nm); ts += p[kk]; }
        l_r = l_r * corr + ts;
        m_r = nm;
        #pragma unroll
        for (int c = 0; c < 64; ++c) o[c] *= corr;
        const int cb = tc * 64;
        #pragma unroll
        for (int kk = 0; kk < KT; ++kk) {
            const float pk = p[kk];
            #pragma unroll
            for (int c = 0; c < 64; c += 4) {
                const float4 vv = *(const float4*)&vs[kk][cb + c];
                o[c + 0] += pk * vv.x; o[c + 1] += pk * vv.y;
                o[c + 2] += pk * vv.z; o[c + 3] += pk * vv.w;
            }
        }
    }

    const float inv = 1.f / l_r;
    const size_t ooff = ((size_t)b * LL + q0 + r) * OUTC + tc * 64;
    #pragma unroll
    for (int c = 0; c < 64; c += 4) {
        float4 res;
        res.x = o[c + 0] * inv; res.y = o[c + 1] * inv;
        res.z = o[c + 2] * inv; res.w = o[c + 3] * inv;
        *(float4*)&out[ooff + c] = res;
    }
}

extern "C" void kernel_launch(void* const* d_in, const int* in_sizes, int n_in,
                              void* d_out, int out_size, void* d_ws, size_t ws_size,
                              hipStream_t stream) {
    const float* x  = (const float*)d_in[0];
    const float* Wq = (const float*)d_in[1];
    const float* bq = (const float*)d_in[2];
    const float* Wk = (const float*)d_in[3];
    const float* bk = (const float*)d_in[4];
    const float* Wv = (const float*)d_in[5];
    const float* bv = (const float*)d_in[6];
    float* out = (float*)d_out;

    // workspace layout (floats): q[1M] | k[1M] | v[8M]  => 40 MB
    float* qb = (float*)d_ws;
    float* kb = qb + (size_t)MTOT * DKK;
    float* vb = kb + (size_t)MTOT * DKK;

    dim3 gA(MTOT / 64, (DKK + DKK + OUTC) / 64);   // (256, 10)
    qkv_proj<<<gA, 256, 0, stream>>>(x, Wq, bq, Wk, bk, Wv, bv, qb, kb, vb);

    dim3 gB(LL / QT, BB);                           // (128, 4)
    flash_attn<<<gB, 256, 0, stream>>>(qb, kb, vb, out);
}

// Round 2
// 552.352 us; speedup vs baseline: 15.9945x; 15.9945x over previous
//
#include <hip/hip_runtime.h>
#include <hip/hip_bf16.h>

#define BB 4
#define LL 4096
#define CC 512
#define DKK 64
#define OUTC 512
#define MTOT (BB*LL)   // 16384

typedef __attribute__((ext_vector_type(8))) short short8;
typedef __attribute__((ext_vector_type(4))) float f32x4;

__device__ __forceinline__ unsigned short f2bf(float f) {
    __hip_bfloat16 h = __float2bfloat16(f);
    return *reinterpret_cast<unsigned short*>(&h);
}

// ---------------- Kernel A: fused QKV projection (fp32 math, bf16 out) ----
// q: bf16 [MTOT][64] row-major
// k: bf16 [MTOT][64] row-major
// v: bf16 TRANSPOSED [B][OUTC][LL]
__global__ __launch_bounds__(256) void qkv_proj(
    const float* __restrict__ x,
    const float* __restrict__ Wq, const float* __restrict__ bq,
    const float* __restrict__ Wk, const float* __restrict__ bk,
    const float* __restrict__ Wv, const float* __restrict__ bv,
    unsigned short* __restrict__ qout, unsigned short* __restrict__ kout,
    unsigned short* __restrict__ vout)
{
    __shared__ float xs[64][33];
    __shared__ float ws[64][33];
    const int m0 = blockIdx.x * 64;
    const int n0 = blockIdx.y * 64;

    const int kind = (n0 == 0) ? 0 : (n0 == 64) ? 1 : 2;
    const float* Wsrc = (kind == 0) ? Wq : (kind == 1) ? Wk : Wv;
    const float* bsrc = (kind == 0) ? bq : (kind == 1) ? bk : bv;
    const int nloc0 = (kind == 2) ? (n0 - 128) : 0;

    const int tid = threadIdx.x;
    const int ty = tid >> 4;   // 0..15
    const int tx = tid & 15;   // 0..15

    float acc[4][4] = {};

    for (int kc = 0; kc < CC; kc += 32) {
        for (int s = tid; s < 512; s += 256) {
            const int r = s >> 3, c4 = s & 7;
            const float4 t = *(const float4*)&x[(size_t)(m0 + r) * CC + kc + c4 * 4];
            xs[r][c4 * 4 + 0] = t.x; xs[r][c4 * 4 + 1] = t.y;
            xs[r][c4 * 4 + 2] = t.z; xs[r][c4 * 4 + 3] = t.w;
        }
        for (int s = tid; s < 512; s += 256) {
            const int r = s >> 3, c4 = s & 7;
            const float4 t = *(const float4*)&Wsrc[(size_t)(nloc0 + r) * CC + kc + c4 * 4];
            ws[r][c4 * 4 + 0] = t.x; ws[r][c4 * 4 + 1] = t.y;
            ws[r][c4 * 4 + 2] = t.z; ws[r][c4 * 4 + 3] = t.w;
        }
        __syncthreads();
        #pragma unroll
        for (int kk = 0; kk < 32; ++kk) {
            float a[4], b[4];
            #pragma unroll
            for (int i = 0; i < 4; ++i) a[i] = xs[ty * 4 + i][kk];
            #pragma unroll
            for (int j = 0; j < 4; ++j) b[j] = ws[tx * 4 + j][kk];
            #pragma unroll
            for (int i = 0; i < 4; ++i)
                #pragma unroll
                for (int j = 0; j < 4; ++j)
                    acc[i][j] += a[i] * b[j];
        }
        __syncthreads();
    }

    if (kind == 2) {
        const int bb = m0 >> 12;              // batch
        const int l0 = (m0 & (LL - 1)) + ty * 4;
        #pragma unroll
        for (int j = 0; j < 4; ++j) {
            const int nl = nloc0 + tx * 4 + j;
            const float bias = bsrc[nl];
            ushort4 pk;
            pk.x = f2bf(acc[0][j] + bias);
            pk.y = f2bf(acc[1][j] + bias);
            pk.z = f2bf(acc[2][j] + bias);
            pk.w = f2bf(acc[3][j] + bias);
            *(ushort4*)&vout[((size_t)(bb * OUTC + nl)) * LL + l0] = pk;
        }
    } else {
        unsigned short* dst = (kind == 0) ? qout : kout;
        #pragma unroll
        for (int i = 0; i < 4; ++i) {
            const int m = m0 + ty * 4 + i;
            ushort4 pk;
            pk.x = f2bf(acc[i][0] + bsrc[tx * 4 + 0]);
            pk.y = f2bf(acc[i][1] + bsrc[tx * 4 + 1]);
            pk.z = f2bf(acc[i][2] + bsrc[tx * 4 + 2]);
            pk.w = f2bf(acc[i][3] + bsrc[tx * 4 + 3]);
            *(ushort4*)&dst[(size_t)m * DKK + tx * 4] = pk;
        }
    }
}

// ---------------- Kernel B: causal flash attention, bf16 MFMA -------------
// Block: 512 threads = 8 waves = 2 q-subtiles x 4 out-quarters.
// QBLK=32 rows, KT=32 keys. Grid: (64 pair-ids, 4 batches); block handles
// q-tiles {pid, 127-pid} sequentially -> every block does exactly 129 k-tiles.
__global__ __launch_bounds__(512) void attn_mfma(
    const unsigned short* __restrict__ qb,
    const unsigned short* __restrict__ kb,
    const unsigned short* __restrict__ vtb,
    float* __restrict__ out)
{
    __shared__ unsigned short Kl[32][72];        // 4.6 KB (padded rows: 144 B)
    __shared__ unsigned short Vt[OUTC][40];      // 40 KB  (padded rows: 80 B)
    __shared__ unsigned short Pl[8][16][40];     // 10.2 KB per-wave P buffers

    const int tid  = threadIdx.x;
    const int wid  = tid >> 6;
    const int lane = tid & 63;
    const int col  = lane & 15;     // frag col / A-frag row
    const int lg   = lane >> 4;     // lane group 0..3
    const int qs   = wid >> 2;      // q subtile 0..1
    const int oq   = wid & 3;       // out quarter 0..3 (128 cols each)
    const int b    = blockIdx.y;
    const int pid  = blockIdx.x;    // 0..63

    for (int phase = 0; phase < 2; ++phase) {
        const int qt = (phase == 0) ? pid : 127 - pid;
        const int q0 = qt * 32;

        // Q fragments (A-frag: row = col, k = lg*8 + i), held in regs
        const unsigned short* qrow = qb + (size_t)(b * LL + q0 + qs * 16 + col) * DKK;
        const short8 qf0 = *(const short8*)&qrow[lg * 8];
        const short8 qf1 = *(const short8*)&qrow[32 + lg * 8];

        f32x4 acc[8];
        #pragma unroll
        for (int i = 0; i < 8; ++i) acc[i] = (f32x4){0.f, 0.f, 0.f, 0.f};
        float m_r[4] = {-1e30f, -1e30f, -1e30f, -1e30f};
        float l_r[4] = {0.f, 0.f, 0.f, 0.f};

        const int ntile = qt + 1;
        for (int t = 0; t < ntile; ++t) {
            const int k0 = t * 32;
            __syncthreads();   // prev iter done reading Kl/Vt
            // stage K tile: 32 rows x 64 bf16, fully coalesced
            if (tid < 256) {
                const int r = tid >> 3, ch = tid & 7;
                *(int4*)&Kl[r][ch * 8] =
                    *(const int4*)&kb[(size_t)(b * LL + k0 + r) * DKK + ch * 8];
            }
            // stage Vt tile: 512 o-rows x 32 bf16 (64 B contiguous per thread)
            {
                const int4* vsrc = (const int4*)&vtb[(size_t)(b * OUTC + tid) * LL + k0];
                const int4 v0 = vsrc[0], v1 = vsrc[1], v2 = vsrc[2], v3 = vsrc[3];
                *(int4*)&Vt[tid][0]  = v0;
                *(int4*)&Vt[tid][8]  = v1;
                *(int4*)&Vt[tid][16] = v2;
                *(int4*)&Vt[tid][24] = v3;
            }
            __syncthreads();

            // QK^T: S[16q x 32k] for this wave's q-subtile
            f32x4 s0 = {0.f, 0.f, 0.f, 0.f}, s1 = {0.f, 0.f, 0.f, 0.f};
            {
                const short8 k00 = *(const short8*)&Kl[col][lg * 8];
                const short8 k01 = *(const short8*)&Kl[col][32 + lg * 8];
                s0 = __builtin_amdgcn_mfma_f32_16x16x32_bf16(qf0, k00, s0, 0, 0, 0);
                s0 = __builtin_amdgcn_mfma_f32_16x16x32_bf16(qf1, k01, s0, 0, 0, 0);
                const short8 k10 = *(const short8*)&Kl[16 + col][lg * 8];
                const short8 k11 = *(const short8*)&Kl[16 + col][32 + lg * 8];
                s1 = __builtin_amdgcn_mfma_f32_16x16x32_bf16(qf0, k10, s1, 0, 0, 0);
                s1 = __builtin_amdgcn_mfma_f32_16x16x32_bf16(qf1, k11, s1, 0, 0, 0);
            }
            // scale + causal mask (C-layout: row = lg*4+reg, col = lane&15)
            const int qrow0 = q0 + qs * 16 + lg * 4;
            #pragma unroll
            for (int r = 0; r < 4; ++r) {
                float a = s0[r] * 0.125f;
                float c = s1[r] * 0.125f;
                if (k0 + col      > qrow0 + r) a = -1e30f;
                if (k0 + 16 + col > qrow0 + r) c = -1e30f;
                s0[r] = a; s1[r] = c;
            }
            // online softmax: row stats via 16-lane shfl_xor reduce
            float mx[4], p0[4], p1[4], sum[4], corr[4];
            #pragma unroll
            for (int r = 0; r < 4; ++r) mx[r] = fmaxf(s0[r], s1[r]);
            #pragma unroll
            for (int d = 1; d < 16; d <<= 1)
                #pragma unroll
                for (int r = 0; r < 4; ++r) mx[r] = fmaxf(mx[r], __shfl_xor(mx[r], d));
            #pragma unroll
            for (int r = 0; r < 4; ++r) {
                const float mn = fmaxf(m_r[r], mx[r]);
                corr[r] = __expf(m_r[r] - mn);
                m_r[r] = mn;
                p0[r] = __expf(s0[r] - mn);
                p1[r] = __expf(s1[r] - mn);
                sum[r] = p0[r] + p1[r];
            }
            #pragma unroll
            for (int d = 1; d < 16; d <<= 1)
                #pragma unroll
                for (int r = 0; r < 4; ++r) sum[r] += __shfl_xor(sum[r], d);
            #pragma unroll
            for (int r = 0; r < 4; ++r) l_r[r] = l_r[r] * corr[r] + sum[r];
            #pragma unroll
            for (int of = 0; of < 8; ++of)
                #pragma unroll
                for (int r = 0; r < 4; ++r) acc[of][r] *= corr[r];

            // P (bf16) -> per-wave LDS buffer, C-layout positions
            #pragma unroll
            for (int r = 0; r < 4; ++r) {
                Pl[wid][lg * 4 + r][col]      = f2bf(p0[r]);
                Pl[wid][lg * 4 + r][16 + col] = f2bf(p1[r]);
            }
            // PV: A-frag = P[q=col][k=lg*8+i], B-frag = Vt[o=base+col][k=lg*8+i]
            const short8 pf = *(const short8*)&Pl[wid][col][lg * 8];
            #pragma unroll
            for (int of = 0; of < 8; ++of) {
                const int o = oq * 128 + of * 16 + col;
                const short8 vf = *(const short8*)&Vt[o][lg * 8];
                acc[of] = __builtin_amdgcn_mfma_f32_16x16x32_bf16(pf, vf, acc[of], 0, 0, 0);
            }
        }

        // epilogue: normalize and store fp32
        #pragma unroll
        for (int r = 0; r < 4; ++r) {
            const float inv = 1.f / l_r[r];
            float* orow = out + (size_t)(b * LL + q0 + qs * 16 + lg * 4 + r) * OUTC
                        + oq * 128;
            #pragma unroll
            for (int of = 0; of < 8; ++of)
                orow[of * 16 + col] = acc[of][r] * inv;
        }
    }
}

extern "C" void kernel_launch(void* const* d_in, const int* in_sizes, int n_in,
                              void* d_out, int out_size, void* d_ws, size_t ws_size,
                              hipStream_t stream) {
    const float* x  = (const float*)d_in[0];
    const float* Wq = (const float*)d_in[1];
    const float* bq = (const float*)d_in[2];
    const float* Wk = (const float*)d_in[3];
    const float* bk = (const float*)d_in[4];
    const float* Wv = (const float*)d_in[5];
    const float* bv = (const float*)d_in[6];
    float* out = (float*)d_out;

    // workspace (ushort): q[1M] | k[1M] | vT[8M]  => 20 MB
    unsigned short* qb  = (unsigned short*)d_ws;
    unsigned short* kbf = qb + (size_t)MTOT * DKK;
    unsigned short* vtb = kbf + (size_t)MTOT * DKK;

    dim3 gA(MTOT / 64, (DKK + DKK + OUTC) / 64);   // (256, 10)
    qkv_proj<<<gA, 256, 0, stream>>>(x, Wq, bq, Wk, bk, Wv, bv, qb, kbf, vtb);

    dim3 gB(64, BB);                                // 256 blocks, balanced pairs
    attn_mfma<<<gB, 512, 0, stream>>>(qb, kbf, vtb, out);
}

// Round 3
// 330.736 us; speedup vs baseline: 26.7120x; 1.6701x over previous
//
#include <hip/hip_runtime.h>
#include <hip/hip_bf16.h>

#define BB 4
#define LL 4096
#define CC 512
#define DKK 64
#define OUTC 512
#define MTOT (BB*LL)   // 16384
#define NTOT (DKK+DKK+OUTC)  // 640

typedef __attribute__((ext_vector_type(8))) short short8;
typedef __attribute__((ext_vector_type(4))) float f32x4;

__device__ __forceinline__ unsigned short f2bf(float f) {
    __hip_bfloat16 h = __float2bfloat16(f);
    return *reinterpret_cast<unsigned short*>(&h);
}
__device__ __forceinline__ unsigned pk2(float a, float b) {
    return (unsigned)f2bf(a) | ((unsigned)f2bf(b) << 16);
}

// ---------------- Kernel 0: convert x and W to bf16 ----------------
// xb: [16384][512] bf16 ; wb: [640][512] bf16 (rows: Wq 0-63, Wk 64-127, Wv 128-639)
__global__ __launch_bounds__(256) void cvt_inputs(
    const float* __restrict__ x, const float* __restrict__ Wq,
    const float* __restrict__ Wk, const float* __restrict__ Wv,
    unsigned short* __restrict__ xb, unsigned short* __restrict__ wb)
{
    const int NX4 = (MTOT * CC) / 4;      // 2097152
    const int NW4 = (NTOT * CC) / 4;      // 81920
    const int i = blockIdx.x * 256 + threadIdx.x;
    if (i >= NX4 + NW4) return;
    float4 t;
    ushort4 p;
    if (i < NX4) {
        t = ((const float4*)x)[i];
        p.x = f2bf(t.x); p.y = f2bf(t.y); p.z = f2bf(t.z); p.w = f2bf(t.w);
        ((ushort4*)xb)[i] = p;
    } else {
        const int wi = i - NX4;
        const int e = wi * 4;
        const float* src = (e < 64 * CC) ? (Wq + e)
                         : (e < 128 * CC) ? (Wk + (e - 64 * CC))
                         : (Wv + (e - 128 * CC));
        t = *(const float4*)src;
        p.x = f2bf(t.x); p.y = f2bf(t.y); p.z = f2bf(t.z); p.w = f2bf(t.w);
        ((ushort4*)wb)[wi] = p;
    }
}

// ---------------- Kernel 1: projection GEMM (bf16 MFMA) ----------------
// C[m][n] = sum_c xb[m][c]*wb[n][c] + bias; 128x128 tile, 4 waves (2x2),
// global_load_lds staging with XOR-swizzled source (rule 21).
__global__ __launch_bounds__(256, 2) void proj_gemm(
    const unsigned short* __restrict__ xb, const unsigned short* __restrict__ wb,
    const float* __restrict__ bq, const float* __restrict__ bk,
    const float* __restrict__ bv,
    unsigned short* __restrict__ qo, unsigned short* __restrict__ ko,
    unsigned short* __restrict__ vt)
{
    __shared__ unsigned short As[128 * 64];
    __shared__ unsigned short Bs[128 * 64];

    const int tid = threadIdx.x;
    const int wid = tid >> 6, lane = tid & 63;
    const int col = lane & 15, lg = lane >> 4;
    const int wm = wid >> 1, wn = wid & 1;
    const int m0 = blockIdx.x * 128, n0 = blockIdx.y * 128;

    f32x4 acc[4][4];
    #pragma unroll
    for (int i = 0; i < 4; ++i)
        #pragma unroll
        for (int j = 0; j < 4; ++j) acc[i][j] = (f32x4){0.f, 0.f, 0.f, 0.f};

    auto* As3 = (__attribute__((address_space(3))) unsigned short*)As;
    auto* Bs3 = (__attribute__((address_space(3))) unsigned short*)Bs;

    for (int kt = 0; kt < CC / 64; ++kt) {
        __syncthreads();
        // stage A and B: 16 chunks of 1 KB each; LDS linear, source pre-swizzled
        #pragma unroll
        for (int i = 0; i < 4; ++i) {
            const int ch = wid * 4 + i;            // 0..15
            const int r = ch * 8 + (lane >> 3);    // 0..127
            const int c4 = lane & 7;
            const int sc4 = c4 ^ (r & 7);
            const unsigned short* ga = xb + (size_t)(m0 + r) * CC + kt * 64 + sc4 * 8;
            __builtin_amdgcn_global_load_lds(
                (const __attribute__((address_space(1))) void*)ga,
                (__attribute__((address_space(3))) void*)(As3 + ch * 512), 16, 0, 0);
            const unsigned short* gb = wb + (size_t)(n0 + r) * CC + kt * 64 + sc4 * 8;
            __builtin_amdgcn_global_load_lds(
                (const __attribute__((address_space(1))) void*)gb,
                (__attribute__((address_space(3))) void*)(Bs3 + ch * 512), 16, 0, 0);
        }
        __syncthreads();   // drains vmcnt -> LDS filled

        #pragma unroll
        for (int kk = 0; kk < 2; ++kk) {
            short8 af[4], bf[4];
            #pragma unroll
            for (int mf = 0; mf < 4; ++mf) {
                const int r = wm * 64 + mf * 16 + col;
                int off = r * 128 + kk * 64 + lg * 16;
                off ^= (r & 7) << 4;
                af[mf] = *(const short8*)((const char*)As + off);
            }
            #pragma unroll
            for (int nf = 0; nf < 4; ++nf) {
                const int r = wn * 64 + nf * 16 + col;
                int off = r * 128 + kk * 64 + lg * 16;
                off ^= (r & 7) << 4;
                bf[nf] = *(const short8*)((const char*)Bs + off);
            }
            #pragma unroll
            for (int mf = 0; mf < 4; ++mf)
                #pragma unroll
                for (int nf = 0; nf < 4; ++nf)
                    acc[mf][nf] = __builtin_amdgcn_mfma_f32_16x16x32_bf16(
                        af[mf], bf[nf], acc[mf][nf], 0, 0, 0);
        }
    }

    // epilogue
    const int nBase = n0 + wn * 64;
    #pragma unroll
    for (int nf = 0; nf < 4; ++nf) {
        const int n = nBase + nf * 16 + col;
        if (n < 64) {
            const float bias = bq[n];
            #pragma unroll
            for (int mf = 0; mf < 4; ++mf) {
                const int m = m0 + wm * 64 + mf * 16 + lg * 4;
                #pragma unroll
                for (int r = 0; r < 4; ++r)
                    qo[(size_t)(m + r) * DKK + n] = f2bf(acc[mf][nf][r] + bias);
            }
        } else if (n < 128) {
            const float bias = bk[n - 64];
            #pragma unroll
            for (int mf = 0; mf < 4; ++mf) {
                const int m = m0 + wm * 64 + mf * 16 + lg * 4;
                #pragma unroll
                for (int r = 0; r < 4; ++r)
                    ko[(size_t)(m + r) * DKK + (n - 64)] = f2bf(acc[mf][nf][r] + bias);
            }
        } else {
            const int o = n - 128;
            const float bias = bv[o];
            const int b = m0 >> 12;
            const int l0 = (m0 & (LL - 1)) + wm * 64;
            #pragma unroll
            for (int mf = 0; mf < 4; ++mf) {
                ushort4 p;
                p.x = f2bf(acc[mf][nf][0] + bias);
                p.y = f2bf(acc[mf][nf][1] + bias);
                p.z = f2bf(acc[mf][nf][2] + bias);
                p.w = f2bf(acc[mf][nf][3] + bias);
                *(ushort4*)&vt[((size_t)(b * OUTC + o)) * LL + l0 + mf * 16 + lg * 4] = p;
            }
        }
    }
}

// ---------------- Kernel 2: causal flash attention, bf16 MFMA -------------
// 512 thr = 8 waves = 2 q-subtiles x 4 out-quarters. One q-tile (32 rows)
// per block; grid (128,4) heavy-first. Swapped QK^T (lane owns q=col),
// T14 async stage (load t+1 to regs before computing t).
__global__ __launch_bounds__(512, 4) void attn_mfma(
    const unsigned short* __restrict__ qb,
    const unsigned short* __restrict__ kb,
    const unsigned short* __restrict__ vtb,
    float* __restrict__ out)
{
    __shared__ unsigned short Kl[32][72];        // 4.6 KB
    __shared__ unsigned short Vt[OUTC][40];      // 40 KB
    __shared__ unsigned short Pl[8][16][40];     // 10.25 KB

    const int tid  = threadIdx.x;
    const int wid  = tid >> 6;
    const int lane = tid & 63;
    const int col  = lane & 15;
    const int lg   = lane >> 4;
    const int qs   = wid >> 2;
    const int oq   = wid & 3;
    const int b    = blockIdx.y;
    const int qt   = 127 - blockIdx.x;    // heavy blocks dispatch first
    const int q0   = qt * 32;

    // Q fragments (B-frag for swapped QK^T): Q[q=col][d=lg*8+i]
    const unsigned short* qrow = qb + (size_t)(b * LL + q0 + qs * 16 + col) * DKK;
    const short8 qf0 = *(const short8*)&qrow[lg * 8];
    const short8 qf1 = *(const short8*)&qrow[32 + lg * 8];

    f32x4 acc[8];
    #pragma unroll
    for (int i = 0; i < 8; ++i) acc[i] = (f32x4){0.f, 0.f, 0.f, 0.f};
    float m_r = -1e30f, l_r = 0.f;

    const int kr = tid >> 3, kc = tid & 7;   // K-stage coords (tid<256)
    int4 kreg;
    int4 vreg0, vreg1, vreg2, vreg3;
    // prologue: load tile 0
    {
        if (tid < 256)
            kreg = *(const int4*)&kb[(size_t)(b * LL + kr) * DKK + kc * 8];
        const int4* vsrc = (const int4*)&vtb[((size_t)(b * OUTC + tid)) * LL];
        vreg0 = vsrc[0]; vreg1 = vsrc[1]; vreg2 = vsrc[2]; vreg3 = vsrc[3];
    }

    const int ntile = qt + 1;
    for (int t = 0; t < ntile; ++t) {
        const int k0 = t * 32;
        __syncthreads();                       // prev tile fully consumed
        if (tid < 256) *(int4*)&Kl[kr][kc * 8] = kreg;
        *(int4*)&Vt[tid][0]  = vreg0;
        *(int4*)&Vt[tid][8]  = vreg1;
        *(int4*)&Vt[tid][16] = vreg2;
        *(int4*)&Vt[tid][24] = vreg3;
        if (t + 1 < ntile) {                   // T14: issue next loads now
            const int kn = (t + 1) * 32;
            if (tid < 256)
                kreg = *(const int4*)&kb[(size_t)(b * LL + kn + kr) * DKK + kc * 8];
            const int4* vsrc = (const int4*)&vtb[((size_t)(b * OUTC + tid)) * LL + kn];
            vreg0 = vsrc[0]; vreg1 = vsrc[1]; vreg2 = vsrc[2]; vreg3 = vsrc[3];
        }
        __syncthreads();                       // LDS ready

        // swapped QK^T: St[k][q], A=K-frag, B=Q-frag
        f32x4 s0 = {0.f, 0.f, 0.f, 0.f}, s1 = {0.f, 0.f, 0.f, 0.f};
        {
            const short8 a00 = *(const short8*)&Kl[col][lg * 8];
            const short8 a01 = *(const short8*)&Kl[col][32 + lg * 8];
            s0 = __builtin_amdgcn_mfma_f32_16x16x32_bf16(a00, qf0, s0, 0, 0, 0);
            s0 = __builtin_amdgcn_mfma_f32_16x16x32_bf16(a01, qf1, s0, 0, 0, 0);
            const short8 a10 = *(const short8*)&Kl[16 + col][lg * 8];
            const short8 a11 = *(const short8*)&Kl[16 + col][32 + lg * 8];
            s1 = __builtin_amdgcn_mfma_f32_16x16x32_bf16(a10, qf0, s1, 0, 0, 0);
            s1 = __builtin_amdgcn_mfma_f32_16x16x32_bf16(a11, qf1, s1, 0, 0, 0);
        }
        // lane owns q = col; k = k0 + lg*4 + r (s0) / +16 (s1)
        const int qg = q0 + qs * 16 + col;
        float sv[8];
        #pragma unroll
        for (int r = 0; r < 4; ++r) {
            const int kg = k0 + lg * 4 + r;
            float v0 = s0[r] * 0.125f;
            float v1 = s1[r] * 0.125f;
            if (kg > qg)      v0 = -1e30f;
            if (kg + 16 > qg) v1 = -1e30f;
            sv[r] = v0; sv[4 + r] = v1;
        }
        float mx = sv[0];
        #pragma unroll
        for (int i = 1; i < 8; ++i) mx = fmaxf(mx, sv[i]);
        mx = fmaxf(mx, __shfl_xor(mx, 16));
        mx = fmaxf(mx, __shfl_xor(mx, 32));
        const float mn = fmaxf(m_r, mx);
        const float corr = __expf(m_r - mn);
        m_r = mn;
        float p[8], sum = 0.f;
        #pragma unroll
        for (int i = 0; i < 8; ++i) { p[i] = __expf(sv[i] - mn); sum += p[i]; }
        sum += __shfl_xor(sum, 16);
        sum += __shfl_xor(sum, 32);
        l_r = l_r * corr + sum;
        // redistribute corr to acc rows (q = lg*4 + r)
        float c4[4];
        #pragma unroll
        for (int r = 0; r < 4; ++r) c4[r] = __shfl(corr, lg * 20 + r);
        #pragma unroll
        for (int of = 0; of < 8; ++of)
            #pragma unroll
            for (int r = 0; r < 4; ++r) acc[of][r] *= c4[r];

        // P -> LDS (packed b64 writes), then read back as A-frag
        {
            uint2 w0, w1;
            w0.x = pk2(p[0], p[1]); w0.y = pk2(p[2], p[3]);
            w1.x = pk2(p[4], p[5]); w1.y = pk2(p[6], p[7]);
            *(uint2*)&Pl[wid][col][lg * 4]      = w0;
            *(uint2*)&Pl[wid][col][16 + lg * 4] = w1;
        }
        const short8 pf = *(const short8*)&Pl[wid][col][lg * 8];
        #pragma unroll
        for (int of = 0; of < 8; ++of) {
            const int o = oq * 128 + of * 16 + col;
            const short8 vf = *(const short8*)&Vt[o][lg * 8];
            acc[of] = __builtin_amdgcn_mfma_f32_16x16x32_bf16(pf, vf, acc[of], 0, 0, 0);
        }
    }

    // epilogue
    const float inv = 1.f / l_r;
    float i4[4];
    #pragma unroll
    for (int r = 0; r < 4; ++r) i4[r] = __shfl(inv, lg * 20 + r);
    #pragma unroll
    for (int r = 0; r < 4; ++r) {
        float* orow = out + (size_t)(b * LL + q0 + qs * 16 + lg * 4 + r) * OUTC
                    + oq * 128;
        #pragma unroll
        for (int of = 0; of < 8; ++of)
            orow[of * 16 + col] = acc[of][r] * i4[r];
    }
}

extern "C" void kernel_launch(void* const* d_in, const int* in_sizes, int n_in,
                              void* d_out, int out_size, void* d_ws, size_t ws_size,
                              hipStream_t stream) {
    const float* x  = (const float*)d_in[0];
    const float* Wq = (const float*)d_in[1];
    const float* bq = (const float*)d_in[2];
    const float* Wk = (const float*)d_in[3];
    const float* bk = (const float*)d_in[4];
    const float* Wv = (const float*)d_in[5];
    const float* bv = (const float*)d_in[6];
    float* out = (float*)d_out;

    // ws layout (ushort): xb[8M] | wb[320K] | q[1M] | k[1M] | vT[8M]  = 38.4 MB
    unsigned short* xb  = (unsigned short*)d_ws;
    unsigned short* wb  = xb + (size_t)MTOT * CC;
    unsigned short* qbf = wb + (size_t)NTOT * CC;
    unsigned short* kbf = qbf + (size_t)MTOT * DKK;
    unsigned short* vtb = kbf + (size_t)MTOT * DKK;

    const int total4 = (MTOT * CC + NTOT * CC) / 4;
    cvt_inputs<<<(total4 + 255) / 256, 256, 0, stream>>>(x, Wq, Wk, Wv, xb, wb);

    dim3 gG(MTOT / 128, NTOT / 128);   // (128, 5)
    proj_gemm<<<gG, 256, 0, stream>>>(xb, wb, bq, bk, bv, qbf, kbf, vtb);

    dim3 gB(LL / 32, BB);              // (128, 4)
    attn_mfma<<<gB, 512, 0, stream>>>(qbf, kbf, vtb, out);
}

// Round 5
// 263.729 us; speedup vs baseline: 33.4989x; 1.2541x over previous
//
#include <hip/hip_runtime.h>
#include <hip/hip_bf16.h>

#define BB 4
#define LL 4096
#define CC 512
#define DKK 64
#define OUTC 512
#define MTOT (BB*LL)         // 16384
#define NTOT (DKK+DKK+OUTC)  // 640

typedef __attribute__((ext_vector_type(8))) short short8;
typedef __attribute__((ext_vector_type(4))) float f32x4;
typedef __attribute__((ext_vector_type(16))) float f32x16;

// q is pre-scaled by 1/sqrt(dk) * log2(e) so attention uses exp2 directly.
#define QSCALE 0.18033688011112042f

__device__ __forceinline__ unsigned short f2bf(float f) {
    __hip_bfloat16 h = __float2bfloat16(f);
    return *reinterpret_cast<unsigned short*>(&h);
}

// pair (lane i <-> lane i+32) reductions via permlane32_swap builtin
__device__ __forceinline__ float pswap_max(float x) {
    unsigned u = __float_as_uint(x);
    auto r = __builtin_amdgcn_permlane32_swap(u, u, false, false);
    return fmaxf(__uint_as_float(r[0]), __uint_as_float(r[1]));
}
__device__ __forceinline__ float pswap_sum(float x) {
    unsigned u = __float_as_uint(x);
    auto r = __builtin_amdgcn_permlane32_swap(u, u, false, false);
    return __uint_as_float(r[0]) + __uint_as_float(r[1]);
}

// ---------------- Kernel 0: convert x and W to bf16 ----------------
__global__ __launch_bounds__(256) void cvt_inputs(
    const float* __restrict__ x, const float* __restrict__ Wq,
    const float* __restrict__ Wk, const float* __restrict__ Wv,
    unsigned short* __restrict__ xb, unsigned short* __restrict__ wb)
{
    const int NX4 = (MTOT * CC) / 4;
    const int NW4 = (NTOT * CC) / 4;
    const int i = blockIdx.x * 256 + threadIdx.x;
    if (i >= NX4 + NW4) return;
    float4 t;
    ushort4 p;
    if (i < NX4) {
        t = ((const float4*)x)[i];
        p.x = f2bf(t.x); p.y = f2bf(t.y); p.z = f2bf(t.z); p.w = f2bf(t.w);
        ((ushort4*)xb)[i] = p;
    } else {
        const int wi = i - NX4;
        const int e = wi * 4;
        const float* src = (e < 64 * CC) ? (Wq + e)
                         : (e < 128 * CC) ? (Wk + (e - 64 * CC))
                         : (Wv + (e - 128 * CC));
        t = *(const float4*)src;
        p.x = f2bf(t.x); p.y = f2bf(t.y); p.z = f2bf(t.z); p.w = f2bf(t.w);
        ((ushort4*)wb)[wi] = p;
    }
}

// ---------------- Kernel 1: projection GEMM (bf16 MFMA) ----------------
__global__ __launch_bounds__(256, 2) void proj_gemm(
    const unsigned short* __restrict__ xb, const unsigned short* __restrict__ wb,
    const float* __restrict__ bq, const float* __restrict__ bk,
    const float* __restrict__ bv,
    unsigned short* __restrict__ qo, unsigned short* __restrict__ ko,
    unsigned short* __restrict__ vt)
{
    __shared__ unsigned short As[128 * 64];
    __shared__ unsigned short Bs[128 * 64];

    const int tid = threadIdx.x;
    const int wid = tid >> 6, lane = tid & 63;
    const int col = lane & 15, lg = lane >> 4;
    const int wm = wid >> 1, wn = wid & 1;
    const int m0 = blockIdx.x * 128, n0 = blockIdx.y * 128;

    f32x4 acc[4][4];
    #pragma unroll
    for (int i = 0; i < 4; ++i)
        #pragma unroll
        for (int j = 0; j < 4; ++j) acc[i][j] = (f32x4){0.f, 0.f, 0.f, 0.f};

    auto* As3 = (__attribute__((address_space(3))) unsigned short*)As;
    auto* Bs3 = (__attribute__((address_space(3))) unsigned short*)Bs;

    for (int kt = 0; kt < CC / 64; ++kt) {
        __syncthreads();
        #pragma unroll
        for (int i = 0; i < 4; ++i) {
            const int ch = wid * 4 + i;
            const int r = ch * 8 + (lane >> 3);
            const int c4 = lane & 7;
            const int sc4 = c4 ^ (r & 7);
            const unsigned short* ga = xb + (size_t)(m0 + r) * CC + kt * 64 + sc4 * 8;
            __builtin_amdgcn_global_load_lds(
                (const __attribute__((address_space(1))) void*)ga,
                (__attribute__((address_space(3))) void*)(As3 + ch * 512), 16, 0, 0);
            const unsigned short* gb = wb + (size_t)(n0 + r) * CC + kt * 64 + sc4 * 8;
            __builtin_amdgcn_global_load_lds(
                (const __attribute__((address_space(1))) void*)gb,
                (__attribute__((address_space(3))) void*)(Bs3 + ch * 512), 16, 0, 0);
        }
        __syncthreads();

        #pragma unroll
        for (int kk = 0; kk < 2; ++kk) {
            short8 af[4], bf[4];
            #pragma unroll
            for (int mf = 0; mf < 4; ++mf) {
                const int r = wm * 64 + mf * 16 + col;
                int off = r * 128 + kk * 64 + lg * 16;
                off ^= (r & 7) << 4;
                af[mf] = *(const short8*)((const char*)As + off);
            }
            #pragma unroll
            for (int nf = 0; nf < 4; ++nf) {
                const int r = wn * 64 + nf * 16 + col;
                int off = r * 128 + kk * 64 + lg * 16;
                off ^= (r & 7) << 4;
                bf[nf] = *(const short8*)((const char*)Bs + off);
            }
            #pragma unroll
            for (int mf = 0; mf < 4; ++mf)
                #pragma unroll
                for (int nf = 0; nf < 4; ++nf)
                    acc[mf][nf] = __builtin_amdgcn_mfma_f32_16x16x32_bf16(
                        af[mf], bf[nf], acc[mf][nf], 0, 0, 0);
        }
    }

    const int nBase = n0 + wn * 64;
    #pragma unroll
    for (int nf = 0; nf < 4; ++nf) {
        const int n = nBase + nf * 16 + col;
        if (n < 64) {
            const float bias = bq[n];
            #pragma unroll
            for (int mf = 0; mf < 4; ++mf) {
                const int m = m0 + wm * 64 + mf * 16 + lg * 4;
                #pragma unroll
                for (int r = 0; r < 4; ++r)
                    qo[(size_t)(m + r) * DKK + n] = f2bf((acc[mf][nf][r] + bias) * QSCALE);
            }
        } else if (n < 128) {
            const float bias = bk[n - 64];
            #pragma unroll
            for (int mf = 0; mf < 4; ++mf) {
                const int m = m0 + wm * 64 + mf * 16 + lg * 4;
                #pragma unroll
                for (int r = 0; r < 4; ++r)
                    ko[(size_t)(m + r) * DKK + (n - 64)] = f2bf(acc[mf][nf][r] + bias);
            }
        } else {
            const int o = n - 128;
            const float bias = bv[o];
            const int b = m0 >> 12;
            const int l0 = (m0 & (LL - 1)) + wm * 64;
            #pragma unroll
            for (int mf = 0; mf < 4; ++mf) {
                ushort4 p;
                p.x = f2bf(acc[mf][nf][0] + bias);
                p.y = f2bf(acc[mf][nf][1] + bias);
                p.z = f2bf(acc[mf][nf][2] + bias);
                p.w = f2bf(acc[mf][nf][3] + bias);
                *(ushort4*)&vt[((size_t)(b * OUTC + o)) * LL + l0 + mf * 16 + lg * 4] = p;
            }
        }
    }
}

// ---------------- Kernel 2: LDS-free causal flash attention ----------------
// 512 thr = 8 independent waves, each owns (32-q-row tile, 64 out-cols).
// 32x32x16 MFMA, swapped QK^T (lane owns q = lane&31). P built in-register
// via v_cvt_pk_bf16_f32 + permlane32_swap builtin. K/Vt global->reg (L2-hot,
// XCD-pinned per batch). Blocks do q-tile pair {pid, 127-pid}: 129 steps each.
__global__ __launch_bounds__(512, 2) void attn_mfma(
    const unsigned short* __restrict__ qb,
    const unsigned short* __restrict__ kb,
    const unsigned short* __restrict__ vtb,
    float* __restrict__ out)
{
    const int tid  = threadIdx.x;
    const int wid  = tid >> 6;
    const int lane = tid & 63;
    const int m31  = lane & 31;
    const int hi   = lane >> 5;
    const int bid  = blockIdx.x;
    // XCD pinning (round-robin dispatch assumption; perf-only): batch = xcd/2
    const int xcd = bid & 7;
    const int b   = xcd >> 1;
    const int pid = (bid >> 3) * 2 + (xcd & 1);   // 0..63
    const int oB  = wid * 64;

    const unsigned short* Kbase = kb  + (size_t)b * LL * DKK;
    const unsigned short* Vbase = vtb + (size_t)b * OUTC * LL;

    #pragma unroll 1
    for (int phase = 0; phase < 2; ++phase) {
        const int qt = phase ? (127 - pid) : pid;
        const int q0 = qt * 32;
        const int nst = qt + 1;

        // Q B-frags: lane holds Q[q0 + m31][c*16 + hi*8 + i]
        short8 qf[4];
        {
            const unsigned short* qrow = qb + ((size_t)b * LL + q0 + m31) * DKK + hi * 8;
            #pragma unroll
            for (int c = 0; c < 4; ++c) qf[c] = *(const short8*)(qrow + c * 16);
        }

        f32x16 acc0, acc1;
        #pragma unroll
        for (int i = 0; i < 16; ++i) { acc0[i] = 0.f; acc1[i] = 0.f; }
        float m_r = -1e30f, l_r = 0.f;

        short8 kfA[4], vfA[4], kfB[4], vfB[4];

        auto LOADK = [&](int T, short8 (&KF)[4]) {
            const unsigned short* kr = Kbase + (size_t)(T * 32 + m31) * DKK + hi * 8;
            KF[0] = *(const short8*)(kr);
            KF[1] = *(const short8*)(kr + 16);
            KF[2] = *(const short8*)(kr + 32);
            KF[3] = *(const short8*)(kr + 48);
        };
        auto LOADV = [&](int T, short8 (&VF)[4]) {
            const unsigned short* vr0 = Vbase + (size_t)(oB + m31) * LL + T * 32 + hi * 8;
            VF[0] = *(const short8*)(vr0);
            VF[1] = *(const short8*)(vr0 + 16);
            const unsigned short* vr1 = vr0 + 32 * LL;
            VF[2] = *(const short8*)(vr1);
            VF[3] = *(const short8*)(vr1 + 16);
        };

        auto STEP = [&](int T, const short8 (&KF)[4], const short8 (&VF)[4]) {
            // swapped QK^T: D[k][q]; lane owns q = m31, k = (j&3)+8*(j>>2)+4*hi
            f32x16 s;
            #pragma unroll
            for (int i = 0; i < 16; ++i) s[i] = 0.f;
            #pragma unroll
            for (int c = 0; c < 4; ++c)
                s = __builtin_amdgcn_mfma_f32_32x32x16_bf16(KF[c], qf[c], s, 0, 0, 0);

            if (T == nst - 1) {   // diagonal tile: causal mask
                const int qg = q0 + m31;
                const int k0 = T * 32;
                #pragma unroll
                for (int j = 0; j < 16; ++j) {
                    const int kk = k0 + (j & 3) + 8 * (j >> 2) + 4 * hi;
                    if (kk > qg) s[j] = -1e30f;
                }
            }

            float mx = s[0];
            #pragma unroll
            for (int j = 1; j < 16; ++j) mx = fmaxf(mx, s[j]);
            mx = pswap_max(mx);

            if (!__all(mx <= m_r)) {           // defer-rescale
                const float mn = fmaxf(m_r, mx);
                const float corr = exp2f(m_r - mn);
                m_r = mn;
                l_r *= corr;
                #pragma unroll
                for (int i = 0; i < 16; ++i) { acc0[i] *= corr; acc1[i] *= corr; }
            }
            float p[16];
            #pragma unroll
            for (int j = 0; j < 16; ++j) p[j] = exp2f(s[j] - m_r);
            {
                float t0 = (p[0] + p[1]) + (p[2] + p[3]);
                float t1 = (p[4] + p[5]) + (p[6] + p[7]);
                float t2 = (p[8] + p[9]) + (p[10] + p[11]);
                float t3 = (p[12] + p[13]) + (p[14] + p[15]);
                l_r += pswap_sum((t0 + t1) + (t2 + t3));
            }

            // P -> bf16 B-frags in-register
            unsigned a0, a1, b0, b1, a2, a3, b2, b3;
            asm("v_cvt_pk_bf16_f32 %0, %1, %2" : "=v"(a0) : "v"(p[0]),  "v"(p[1]));
            asm("v_cvt_pk_bf16_f32 %0, %1, %2" : "=v"(a1) : "v"(p[2]),  "v"(p[3]));
            asm("v_cvt_pk_bf16_f32 %0, %1, %2" : "=v"(b0) : "v"(p[4]),  "v"(p[5]));
            asm("v_cvt_pk_bf16_f32 %0, %1, %2" : "=v"(b1) : "v"(p[6]),  "v"(p[7]));
            asm("v_cvt_pk_bf16_f32 %0, %1, %2" : "=v"(a2) : "v"(p[8]),  "v"(p[9]));
            asm("v_cvt_pk_bf16_f32 %0, %1, %2" : "=v"(a3) : "v"(p[10]), "v"(p[11]));
            asm("v_cvt_pk_bf16_f32 %0, %1, %2" : "=v"(b2) : "v"(p[12]), "v"(p[13]));
            asm("v_cvt_pk_bf16_f32 %0, %1, %2" : "=v"(b3) : "v"(p[14]), "v"(p[15]));
            auto r0 = __builtin_amdgcn_permlane32_swap(a0, b0, false, false);
            auto r1 = __builtin_amdgcn_permlane32_swap(a1, b1, false, false);
            auto r2 = __builtin_amdgcn_permlane32_swap(a2, b2, false, false);
            auto r3 = __builtin_amdgcn_permlane32_swap(a3, b3, false, false);
            union { unsigned u[4]; short8 s8; } pf0, pf1;
            pf0.u[0] = r0[0]; pf0.u[1] = r1[0]; pf0.u[2] = r0[1]; pf0.u[3] = r1[1];
            pf1.u[0] = r2[0]; pf1.u[1] = r3[0]; pf1.u[2] = r2[1]; pf1.u[3] = r3[1];

            // PV: D[o][q] += Vt-frag x P-frag
            acc0 = __builtin_amdgcn_mfma_f32_32x32x16_bf16(VF[0], pf0.s8, acc0, 0, 0, 0);
            acc0 = __builtin_amdgcn_mfma_f32_32x32x16_bf16(VF[1], pf1.s8, acc0, 0, 0, 0);
            acc1 = __builtin_amdgcn_mfma_f32_32x32x16_bf16(VF[2], pf0.s8, acc1, 0, 0, 0);
            acc1 = __builtin_amdgcn_mfma_f32_32x32x16_bf16(VF[3], pf1.s8, acc1, 0, 0, 0);
        };

        LOADK(0, kfA); LOADV(0, vfA);
        int t = 0;
        for (;;) {
            if (t + 1 < nst) { LOADK(t + 1, kfB); LOADV(t + 1, vfB); }
            STEP(t, kfA, vfA);
            ++t; if (t == nst) break;
            if (t + 1 < nst) { LOADK(t + 1, kfA); LOADV(t + 1, vfA); }
            STEP(t, kfB, vfB);
            ++t; if (t == nst) break;
        }

        // epilogue: lane owns q = q0 + m31; o = oB + ot*32 + 8*g + 4*hi + r
        const float inv = 1.f / l_r;
        float* orow = out + ((size_t)b * LL + q0 + m31) * OUTC + oB + hi * 4;
        #pragma unroll
        for (int g = 0; g < 4; ++g) {
            float4 w0, w1;
            w0.x = acc0[g * 4 + 0] * inv; w0.y = acc0[g * 4 + 1] * inv;
            w0.z = acc0[g * 4 + 2] * inv; w0.w = acc0[g * 4 + 3] * inv;
            *(float4*)(orow + g * 8) = w0;
            w1.x = acc1[g * 4 + 0] * inv; w1.y = acc1[g * 4 + 1] * inv;
            w1.z = acc1[g * 4 + 2] * inv; w1.w = acc1[g * 4 + 3] * inv;
            *(float4*)(orow + 32 + g * 8) = w1;
        }
    }
}

extern "C" void kernel_launch(void* const* d_in, const int* in_sizes, int n_in,
                              void* d_out, int out_size, void* d_ws, size_t ws_size,
                              hipStream_t stream) {
    const float* x  = (const float*)d_in[0];
    const float* Wq = (const float*)d_in[1];
    const float* bq = (const float*)d_in[2];
    const float* Wk = (const float*)d_in[3];
    const float* bk = (const float*)d_in[4];
    const float* Wv = (const float*)d_in[5];
    const float* bv = (const float*)d_in[6];
    float* out = (float*)d_out;

    unsigned short* xb  = (unsigned short*)d_ws;
    unsigned short* wb  = xb + (size_t)MTOT * CC;
    unsigned short* qbf = wb + (size_t)NTOT * CC;
    unsigned short* kbf = qbf + (size_t)MTOT * DKK;
    unsigned short* vtb = kbf + (size_t)MTOT * DKK;

    const int total4 = (MTOT * CC + NTOT * CC) / 4;
    cvt_inputs<<<(total4 + 255) / 256, 256, 0, stream>>>(x, Wq, Wk, Wv, xb, wb);

    dim3 gG(MTOT / 128, NTOT / 128);
    proj_gemm<<<gG, 256, 0, stream>>>(xb, wb, bq, bk, bv, qbf, kbf, vtb);

    attn_mfma<<<256, 512, 0, stream>>>(qbf, kbf, vtb, out);
}

// Round 6
// 134.042 us; speedup vs baseline: 65.9094x; 1.9675x over previous
//
#include <hip/hip_runtime.h>
#include <hip/hip_bf16.h>

#define BB 4
#define LL 4096
#define CC 512
#define DKK 64
#define OUTC 512
#define MTOT (BB*LL)         // 16384
#define NTOT (DKK+DKK+OUTC)  // 640

typedef __attribute__((ext_vector_type(8))) short short8;
typedef __attribute__((ext_vector_type(4))) float f32x4;
typedef __attribute__((ext_vector_type(16))) float f32x16;

// q is pre-scaled by 1/sqrt(dk) * log2(e) so attention uses exp2 directly.
#define QSCALE 0.18033688011112042f
#define MSHIFT 12.0f

#if __has_builtin(__builtin_amdgcn_exp2f)
#define EXP2(x) __builtin_amdgcn_exp2f(x)
#else
#define EXP2(x) exp2f(x)
#endif

__device__ __forceinline__ unsigned short f2bf(float f) {
    __hip_bfloat16 h = __float2bfloat16(f);
    return *reinterpret_cast<unsigned short*>(&h);
}

__device__ __forceinline__ float pswap_sum(float x) {
    unsigned u = __float_as_uint(x);
    auto r = __builtin_amdgcn_permlane32_swap(u, u, false, false);
    return __uint_as_float(r[0]) + __uint_as_float(r[1]);
}

// Tiled fragment layouts (all bf16):
//  qtb/ktb [b][T<128][c<4][lane<64][j<8]:
//     element = M[b][T*32 + (lane&31)][c*16 + (lane>>5)*8 + j]
//  vtt [b][T<128][og<8][f<4][lane<64][j<8]:
//     element = V[b][token = T*32 + (f&1)*16 + (lane>>5)*8 + j][o = og*64 + (f>>1)*32 + (lane&31)]

// ---------------- Kernel 0: convert x and W to bf16 ----------------
__global__ __launch_bounds__(256) void cvt_inputs(
    const float* __restrict__ x, const float* __restrict__ Wq,
    const float* __restrict__ Wk, const float* __restrict__ Wv,
    unsigned short* __restrict__ xb, unsigned short* __restrict__ wb)
{
    const int NX4 = (MTOT * CC) / 4;
    const int NW4 = (NTOT * CC) / 4;
    const int i = blockIdx.x * 256 + threadIdx.x;
    if (i >= NX4 + NW4) return;
    float4 t;
    ushort4 p;
    if (i < NX4) {
        t = ((const float4*)x)[i];
        p.x = f2bf(t.x); p.y = f2bf(t.y); p.z = f2bf(t.z); p.w = f2bf(t.w);
        ((ushort4*)xb)[i] = p;
    } else {
        const int wi = i - NX4;
        const int e = wi * 4;
        const float* src = (e < 64 * CC) ? (Wq + e)
                         : (e < 128 * CC) ? (Wk + (e - 64 * CC))
                         : (Wv + (e - 128 * CC));
        t = *(const float4*)src;
        p.x = f2bf(t.x); p.y = f2bf(t.y); p.z = f2bf(t.z); p.w = f2bf(t.w);
        ((ushort4*)wb)[wi] = p;
    }
}

// ---------------- Kernel 1: projection GEMM (bf16 MFMA) ----------------
__global__ __launch_bounds__(256, 2) void proj_gemm(
    const unsigned short* __restrict__ xb, const unsigned short* __restrict__ wb,
    const float* __restrict__ bq, const float* __restrict__ bk,
    const float* __restrict__ bv,
    unsigned short* __restrict__ qo, unsigned short* __restrict__ ko,
    unsigned short* __restrict__ vt)
{
    __shared__ unsigned short As[128 * 64];
    __shared__ unsigned short Bs[128 * 64];

    const int tid = threadIdx.x;
    const int wid = tid >> 6, lane = tid & 63;
    const int col = lane & 15, lg = lane >> 4;
    const int wm = wid >> 1, wn = wid & 1;
    const int m0 = blockIdx.x * 128, n0 = blockIdx.y * 128;

    f32x4 acc[4][4];
    #pragma unroll
    for (int i = 0; i < 4; ++i)
        #pragma unroll
        for (int j = 0; j < 4; ++j) acc[i][j] = (f32x4){0.f, 0.f, 0.f, 0.f};

    auto* As3 = (__attribute__((address_space(3))) unsigned short*)As;
    auto* Bs3 = (__attribute__((address_space(3))) unsigned short*)Bs;

    for (int kt = 0; kt < CC / 64; ++kt) {
        __syncthreads();
        #pragma unroll
        for (int i = 0; i < 4; ++i) {
            const int ch = wid * 4 + i;
            const int r = ch * 8 + (lane >> 3);
            const int c4 = lane & 7;
            const int sc4 = c4 ^ (r & 7);
            const unsigned short* ga = xb + (size_t)(m0 + r) * CC + kt * 64 + sc4 * 8;
            __builtin_amdgcn_global_load_lds(
                (const __attribute__((address_space(1))) void*)ga,
                (__attribute__((address_space(3))) void*)(As3 + ch * 512), 16, 0, 0);
            const unsigned short* gb = wb + (size_t)(n0 + r) * CC + kt * 64 + sc4 * 8;
            __builtin_amdgcn_global_load_lds(
                (const __attribute__((address_space(1))) void*)gb,
                (__attribute__((address_space(3))) void*)(Bs3 + ch * 512), 16, 0, 0);
        }
        __syncthreads();

        #pragma unroll
        for (int kk = 0; kk < 2; ++kk) {
            short8 af[4], bf[4];
            #pragma unroll
            for (int mf = 0; mf < 4; ++mf) {
                const int r = wm * 64 + mf * 16 + col;
                int off = r * 128 + kk * 64 + lg * 16;
                off ^= (r & 7) << 4;
                af[mf] = *(const short8*)((const char*)As + off);
            }
            #pragma unroll
            for (int nf = 0; nf < 4; ++nf) {
                const int r = wn * 64 + nf * 16 + col;
                int off = r * 128 + kk * 64 + lg * 16;
                off ^= (r & 7) << 4;
                bf[nf] = *(const short8*)((const char*)Bs + off);
            }
            #pragma unroll
            for (int mf = 0; mf < 4; ++mf)
                #pragma unroll
                for (int nf = 0; nf < 4; ++nf)
                    acc[mf][nf] = __builtin_amdgcn_mfma_f32_16x16x32_bf16(
                        af[mf], bf[nf], acc[mf][nf], 0, 0, 0);
        }
    }

    // epilogue -> fragment-tiled layouts
    const int nBase = n0 + wn * 64;
    #pragma unroll
    for (int nf = 0; nf < 4; ++nf) {
        const int n = nBase + nf * 16 + col;
        if (n < 128) {
            const bool isQ = (n < 64);
            const int nn = isQ ? n : (n - 64);
            const float bias = isQ ? bq[nn] : bk[nn];
            const float scl = isQ ? QSCALE : 1.0f;
            unsigned short* dst = isQ ? qo : ko;
            const int c = nn >> 4, h8 = (nn >> 3) & 1, jj = nn & 7;
            #pragma unroll
            for (int mf = 0; mf < 4; ++mf) {
                const int m = m0 + wm * 64 + mf * 16 + lg * 4;
                const int b_ = m >> 12;
                const int T = (m & 4095) >> 5;
                const size_t base =
                    ((((size_t)b_ * 128 + T) * 4 + c) * 64) * 8 + jj;
                #pragma unroll
                for (int r = 0; r < 4; ++r) {
                    const int l = (((m + r) & 31) + 32 * h8);
                    dst[base + (size_t)l * 8] = f2bf((acc[mf][nf][r] + bias) * scl);
                }
            }
        } else {
            const int o = n - 128;
            const float bias = bv[o];
            const int og = o >> 6;
            const int fo = (o >> 5) & 1;
            #pragma unroll
            for (int mf = 0; mf < 4; ++mf) {
                const int m = m0 + wm * 64 + mf * 16 + lg * 4;   // token of r=0
                const int b_ = m >> 12;
                const int tl = m & 4095;
                const int T = tl >> 5;
                const int kk = tl & 31;
                const int f = fo * 2 + ((kk >> 4) & 1);
                const int h8 = (kk >> 3) & 1;
                const int jb = kk & 7;                            // 0 or 4
                const int l = (o & 31) + 32 * h8;
                const size_t addr =
                    (((((size_t)b_ * 128 + T) * 8 + og) * 4 + f) * 64 + l) * 8 + jb;
                ushort4 p;
                p.x = f2bf(acc[mf][nf][0] + bias);
                p.y = f2bf(acc[mf][nf][1] + bias);
                p.z = f2bf(acc[mf][nf][2] + bias);
                p.w = f2bf(acc[mf][nf][3] + bias);
                *(ushort4*)&vt[addr] = p;
            }
        }
    }
}

// ---------------- Kernel 2: LDS-free causal flash attention ----------------
// 256 thr = 4 waves; wave owns 64 q-rows x 64 out-cols (og). All loads are
// coalesced 1KB from fragment-tiled layouts. Constant-shift softmax (no max
// tracking). Block handles q-tile pair {p, 63-p}: exactly 130 steps each.
__global__ __launch_bounds__(256) void attn_mfma(
    const unsigned short* __restrict__ qtb,
    const unsigned short* __restrict__ ktb,
    const unsigned short* __restrict__ vtt,
    float* __restrict__ out)
{
    const int tid  = threadIdx.x;
    const int wid  = tid >> 6;
    const int lane = tid & 63;
    const int m31  = lane & 31;
    const int hi   = lane >> 5;
    const int bid  = blockIdx.x;
    // XCD pinning: batch = (bid>>1)&3 -> XCD pair {2b, 2b+1} (perf-only)
    const int b  = (bid >> 1) & 3;
    const int oh = bid & 1;
    const int pp = bid >> 3;          // 0..31
    const int og = oh * 4 + wid;

    const unsigned short* Qb = qtb + (size_t)b * 128 * 2048;
    const unsigned short* Kb = ktb + (size_t)b * 128 * 2048;
    const unsigned short* Vb = vtt + (size_t)b * 128 * 16384;
    float* outb = out + (size_t)b * LL * OUTC;

    #pragma unroll 1
    for (int phase = 0; phase < 2; ++phase) {
        const int jt  = phase ? (63 - pp) : pp;
        const int q0  = jt * 64;
        const int nst = 2 * jt + 2;

        // Q fragments for both q-halves (coalesced 1KB loads)
        short8 qfL[4], qfH[4];
        {
            const unsigned short* pl = Qb + (size_t)(2 * jt) * 2048 + lane * 8;
            const unsigned short* ph = pl + 2048;
            #pragma unroll
            for (int c = 0; c < 4; ++c) {
                qfL[c] = *(const short8*)(pl + c * 512);
                qfH[c] = *(const short8*)(ph + c * 512);
            }
        }

        f32x16 aL0, aL1, aH0, aH1;
        #pragma unroll
        for (int i = 0; i < 16; ++i) { aL0[i]=0.f; aL1[i]=0.f; aH0[i]=0.f; aH1[i]=0.f; }
        float lsL = 0.f, lsH = 0.f;

        short8 kfA[4], vfA[4], kfB[4], vfB[4];

        auto LOADK = [&](int T, short8 (&KF)[4]) {
            const unsigned short* p = Kb + (size_t)T * 2048 + lane * 8;
            KF[0] = *(const short8*)(p);
            KF[1] = *(const short8*)(p + 512);
            KF[2] = *(const short8*)(p + 1024);
            KF[3] = *(const short8*)(p + 1536);
        };
        auto LOADV = [&](int T, short8 (&VF)[4]) {
            const unsigned short* p = Vb + (size_t)T * 16384 + og * 2048 + lane * 8;
            VF[0] = *(const short8*)(p);
            VF[1] = *(const short8*)(p + 512);
            VF[2] = *(const short8*)(p + 1024);
            VF[3] = *(const short8*)(p + 1536);
        };

        // softmax (constant shift) -> P fragments + l partial
        auto SM = [&](f32x16 s, bool diag, float& ls, short8& o0, short8& o1) {
            if (diag) {
                #pragma unroll
                for (int jj = 0; jj < 16; ++jj) {
                    const int pos = (jj & 3) + 8 * (jj >> 2) + 4 * hi;
                    if (pos > m31) s[jj] = -30000.f;
                }
            }
            float p[16];
            #pragma unroll
            for (int jj = 0; jj < 16; ++jj) p[jj] = EXP2(s[jj] - MSHIFT);
            {
                float t0 = (p[0] + p[1]) + (p[2] + p[3]);
                float t1 = (p[4] + p[5]) + (p[6] + p[7]);
                float t2 = (p[8] + p[9]) + (p[10] + p[11]);
                float t3 = (p[12] + p[13]) + (p[14] + p[15]);
                ls += (t0 + t1) + (t2 + t3);
            }
            unsigned a0, a1, b0, b1, a2, a3, b2, b3;
            asm("v_cvt_pk_bf16_f32 %0, %1, %2" : "=v"(a0) : "v"(p[0]),  "v"(p[1]));
            asm("v_cvt_pk_bf16_f32 %0, %1, %2" : "=v"(a1) : "v"(p[2]),  "v"(p[3]));
            asm("v_cvt_pk_bf16_f32 %0, %1, %2" : "=v"(b0) : "v"(p[4]),  "v"(p[5]));
            asm("v_cvt_pk_bf16_f32 %0, %1, %2" : "=v"(b1) : "v"(p[6]),  "v"(p[7]));
            asm("v_cvt_pk_bf16_f32 %0, %1, %2" : "=v"(a2) : "v"(p[8]),  "v"(p[9]));
            asm("v_cvt_pk_bf16_f32 %0, %1, %2" : "=v"(a3) : "v"(p[10]), "v"(p[11]));
            asm("v_cvt_pk_bf16_f32 %0, %1, %2" : "=v"(b2) : "v"(p[12]), "v"(p[13]));
            asm("v_cvt_pk_bf16_f32 %0, %1, %2" : "=v"(b3) : "v"(p[14]), "v"(p[15]));
            auto r0 = __builtin_amdgcn_permlane32_swap(a0, b0, false, false);
            auto r1 = __builtin_amdgcn_permlane32_swap(a1, b1, false, false);
            auto r2 = __builtin_amdgcn_permlane32_swap(a2, b2, false, false);
            auto r3 = __builtin_amdgcn_permlane32_swap(a3, b3, false, false);
            union { unsigned u[4]; short8 s8; } pf0, pf1;
            pf0.u[0] = r0[0]; pf0.u[1] = r1[0]; pf0.u[2] = r0[1]; pf0.u[3] = r1[1];
            pf1.u[0] = r2[0]; pf1.u[1] = r3[0]; pf1.u[2] = r2[1]; pf1.u[3] = r3[1];
            o0 = pf0.s8; o1 = pf1.s8;
        };

        auto STEP = [&](int t, const short8 (&KF)[4], const short8 (&VF)[4]) {
            const bool lo_on = (t <= 2 * jt);
            if (lo_on) {
                f32x16 s;
                #pragma unroll
                for (int i = 0; i < 16; ++i) s[i] = 0.f;
                #pragma unroll
                for (int c = 0; c < 4; ++c)
                    s = __builtin_amdgcn_mfma_f32_32x32x16_bf16(KF[c], qfL[c], s, 0, 0, 0);
                short8 pf0, pf1;
                SM(s, t == 2 * jt, lsL, pf0, pf1);
                aL0 = __builtin_amdgcn_mfma_f32_32x32x16_bf16(VF[0], pf0, aL0, 0, 0, 0);
                aL0 = __builtin_amdgcn_mfma_f32_32x32x16_bf16(VF[1], pf1, aL0, 0, 0, 0);
                aL1 = __builtin_amdgcn_mfma_f32_32x32x16_bf16(VF[2], pf0, aL1, 0, 0, 0);
                aL1 = __builtin_amdgcn_mfma_f32_32x32x16_bf16(VF[3], pf1, aL1, 0, 0, 0);
            }
            {
                f32x16 s;
                #pragma unroll
                for (int i = 0; i < 16; ++i) s[i] = 0.f;
                #pragma unroll
                for (int c = 0; c < 4; ++c)
                    s = __builtin_amdgcn_mfma_f32_32x32x16_bf16(KF[c], qfH[c], s, 0, 0, 0);
                short8 pf0, pf1;
                SM(s, t == 2 * jt + 1, lsH, pf0, pf1);
                aH0 = __builtin_amdgcn_mfma_f32_32x32x16_bf16(VF[0], pf0, aH0, 0, 0, 0);
                aH0 = __builtin_amdgcn_mfma_f32_32x32x16_bf16(VF[1], pf1, aH0, 0, 0, 0);
                aH1 = __builtin_amdgcn_mfma_f32_32x32x16_bf16(VF[2], pf0, aH1, 0, 0, 0);
                aH1 = __builtin_amdgcn_mfma_f32_32x32x16_bf16(VF[3], pf1, aH1, 0, 0, 0);
            }
        };

        LOADK(0, kfA); LOADV(0, vfA);
        int t = 0;
        for (;;) {
            if (t + 1 < nst) { LOADK(t + 1, kfB); LOADV(t + 1, vfB); }
            STEP(t, kfA, vfA);
            ++t; if (t == nst) break;
            if (t + 1 < nst) { LOADK(t + 1, kfA); LOADV(t + 1, vfA); }
            STEP(t, kfB, vfB);
            ++t; if (t == nst) break;
        }

        // epilogue: q = q0 + 32h + m31; o = og*64 + ot*32 + g*8 + 4*hi + r
        {
            const float invL = 1.f / pswap_sum(lsL);
            const float invH = 1.f / pswap_sum(lsH);
            float* rowL = outb + (size_t)(q0 + m31) * OUTC + og * 64 + hi * 4;
            float* rowH = rowL + 32 * OUTC;
            #pragma unroll
            for (int g = 0; g < 4; ++g) {
                float4 w;
                w.x = aL0[g*4+0]*invL; w.y = aL0[g*4+1]*invL;
                w.z = aL0[g*4+2]*invL; w.w = aL0[g*4+3]*invL;
                *(float4*)(rowL + g * 8) = w;
                w.x = aL1[g*4+0]*invL; w.y = aL1[g*4+1]*invL;
                w.z = aL1[g*4+2]*invL; w.w = aL1[g*4+3]*invL;
                *(float4*)(rowL + 32 + g * 8) = w;
                w.x = aH0[g*4+0]*invH; w.y = aH0[g*4+1]*invH;
                w.z = aH0[g*4+2]*invH; w.w = aH0[g*4+3]*invH;
                *(float4*)(rowH + g * 8) = w;
                w.x = aH1[g*4+0]*invH; w.y = aH1[g*4+1]*invH;
                w.z = aH1[g*4+2]*invH; w.w = aH1[g*4+3]*invH;
                *(float4*)(rowH + 32 + g * 8) = w;
            }
        }
    }
}

extern "C" void kernel_launch(void* const* d_in, const int* in_sizes, int n_in,
                              void* d_out, int out_size, void* d_ws, size_t ws_size,
                              hipStream_t stream) {
    const float* x  = (const float*)d_in[0];
    const float* Wq = (const float*)d_in[1];
    const float* bq = (const float*)d_in[2];
    const float* Wk = (const float*)d_in[3];
    const float* bk = (const float*)d_in[4];
    const float* Wv = (const float*)d_in[5];
    const float* bv = (const float*)d_in[6];
    float* out = (float*)d_out;

    unsigned short* xb  = (unsigned short*)d_ws;
    unsigned short* wb  = xb + (size_t)MTOT * CC;
    unsigned short* qbf = wb + (size_t)NTOT * CC;
    unsigned short* kbf = qbf + (size_t)MTOT * DKK;
    unsigned short* vtb = kbf + (size_t)MTOT * DKK;

    const int total4 = (MTOT * CC + NTOT * CC) / 4;
    cvt_inputs<<<(total4 + 255) / 256, 256, 0, stream>>>(x, Wq, Wk, Wv, xb, wb);

    dim3 gG(MTOT / 128, NTOT / 128);
    proj_gemm<<<gG, 256, 0, stream>>>(xb, wb, bq, bk, bv, qbf, kbf, vtb);

    attn_mfma<<<256, 256, 0, stream>>>(qbf, kbf, vtb, out);
}

// Round 7
// 102.040 us; speedup vs baseline: 86.5796x; 1.3136x over previous
//
#include <hip/hip_runtime.h>
#include <hip/hip_bf16.h>

#define BB 4
#define LL 4096
#define CC 512
#define DKK 64
#define OUTC 512
#define MTOT (BB*LL)         // 16384
#define NTOT (DKK+DKK+OUTC)  // 640

typedef __attribute__((ext_vector_type(8))) short short8;
typedef __attribute__((ext_vector_type(4))) float f32x4;
typedef __attribute__((ext_vector_type(16))) float f32x16;

// q is pre-scaled by 1/sqrt(dk) * log2(e) so attention uses exp2 directly.
#define QSCALE 0.18033688011112042f
#define MSHIFT 12.0f

#if __has_builtin(__builtin_amdgcn_exp2f)
#define EXP2(x) __builtin_amdgcn_exp2f(x)
#else
#define EXP2(x) exp2f(x)
#endif

__device__ __forceinline__ unsigned short f2bf(float f) {
    __hip_bfloat16 h = __float2bfloat16(f);
    return *reinterpret_cast<unsigned short*>(&h);
}

__device__ __forceinline__ float pswap_sum(float x) {
    unsigned u = __float_as_uint(x);
    auto r = __builtin_amdgcn_permlane32_swap(u, u, false, false);
    return __uint_as_float(r[0]) + __uint_as_float(r[1]);
}

// Tiled fragment layouts (all bf16):
//  qtb/ktb [b][T<128][c<4][lane<64][j<8]:
//     element = M[b][T*32 + (lane&31)][c*16 + (lane>>5)*8 + j]
//  vtt [b][T<128][og<8][f<4][lane<64][j<8]:
//     element = V[b][token = T*32 + (f&1)*16 + (lane>>5)*8 + j][o = og*64 + (f>>1)*32 + (lane&31)]

// ---------------- Kernel 0: convert x and W to bf16 ----------------
__global__ __launch_bounds__(256) void cvt_inputs(
    const float* __restrict__ x, const float* __restrict__ Wq,
    const float* __restrict__ Wk, const float* __restrict__ Wv,
    unsigned short* __restrict__ xb, unsigned short* __restrict__ wb)
{
    const int NX4 = (MTOT * CC) / 4;
    const int NW4 = (NTOT * CC) / 4;
    const int i = blockIdx.x * 256 + threadIdx.x;
    if (i >= NX4 + NW4) return;
    float4 t;
    ushort4 p;
    if (i < NX4) {
        t = ((const float4*)x)[i];
        p.x = f2bf(t.x); p.y = f2bf(t.y); p.z = f2bf(t.z); p.w = f2bf(t.w);
        ((ushort4*)xb)[i] = p;
    } else {
        const int wi = i - NX4;
        const int e = wi * 4;
        const float* src = (e < 64 * CC) ? (Wq + e)
                         : (e < 128 * CC) ? (Wk + (e - 64 * CC))
                         : (Wv + (e - 128 * CC));
        t = *(const float4*)src;
        p.x = f2bf(t.x); p.y = f2bf(t.y); p.z = f2bf(t.z); p.w = f2bf(t.w);
        ((ushort4*)wb)[wi] = p;
    }
}

// ---------------- Kernel 1: projection GEMM (bf16 MFMA) ----------------
__global__ __launch_bounds__(256, 2) void proj_gemm(
    const unsigned short* __restrict__ xb, const unsigned short* __restrict__ wb,
    const float* __restrict__ bq, const float* __restrict__ bk,
    const float* __restrict__ bv,
    unsigned short* __restrict__ qo, unsigned short* __restrict__ ko,
    unsigned short* __restrict__ vt)
{
    __shared__ unsigned short As[128 * 64];
    __shared__ unsigned short Bs[128 * 64];

    const int tid = threadIdx.x;
    const int wid = tid >> 6, lane = tid & 63;
    const int col = lane & 15, lg = lane >> 4;
    const int wm = wid >> 1, wn = wid & 1;
    const int m0 = blockIdx.x * 128, n0 = blockIdx.y * 128;

    f32x4 acc[4][4];
    #pragma unroll
    for (int i = 0; i < 4; ++i)
        #pragma unroll
        for (int j = 0; j < 4; ++j) acc[i][j] = (f32x4){0.f, 0.f, 0.f, 0.f};

    auto* As3 = (__attribute__((address_space(3))) unsigned short*)As;
    auto* Bs3 = (__attribute__((address_space(3))) unsigned short*)Bs;

    for (int kt = 0; kt < CC / 64; ++kt) {
        __syncthreads();
        #pragma unroll
        for (int i = 0; i < 4; ++i) {
            const int ch = wid * 4 + i;
            const int r = ch * 8 + (lane >> 3);
            const int c4 = lane & 7;
            const int sc4 = c4 ^ (r & 7);
            const unsigned short* ga = xb + (size_t)(m0 + r) * CC + kt * 64 + sc4 * 8;
            __builtin_amdgcn_global_load_lds(
                (const __attribute__((address_space(1))) void*)ga,
                (__attribute__((address_space(3))) void*)(As3 + ch * 512), 16, 0, 0);
            const unsigned short* gb = wb + (size_t)(n0 + r) * CC + kt * 64 + sc4 * 8;
            __builtin_amdgcn_global_load_lds(
                (const __attribute__((address_space(1))) void*)gb,
                (__attribute__((address_space(3))) void*)(Bs3 + ch * 512), 16, 0, 0);
        }
        __syncthreads();

        #pragma unroll
        for (int kk = 0; kk < 2; ++kk) {
            short8 af[4], bf[4];
            #pragma unroll
            for (int mf = 0; mf < 4; ++mf) {
                const int r = wm * 64 + mf * 16 + col;
                int off = r * 128 + kk * 64 + lg * 16;
                off ^= (r & 7) << 4;
                af[mf] = *(const short8*)((const char*)As + off);
            }
            #pragma unroll
            for (int nf = 0; nf < 4; ++nf) {
                const int r = wn * 64 + nf * 16 + col;
                int off = r * 128 + kk * 64 + lg * 16;
                off ^= (r & 7) << 4;
                bf[nf] = *(const short8*)((const char*)Bs + off);
            }
            #pragma unroll
            for (int mf = 0; mf < 4; ++mf)
                #pragma unroll
                for (int nf = 0; nf < 4; ++nf)
                    acc[mf][nf] = __builtin_amdgcn_mfma_f32_16x16x32_bf16(
                        af[mf], bf[nf], acc[mf][nf], 0, 0, 0);
        }
    }

    // epilogue -> fragment-tiled layouts
    const int nBase = n0 + wn * 64;
    #pragma unroll
    for (int nf = 0; nf < 4; ++nf) {
        const int n = nBase + nf * 16 + col;
        if (n < 128) {
            const bool isQ = (n < 64);
            const int nn = isQ ? n : (n - 64);
            const float bias = isQ ? bq[nn] : bk[nn];
            const float scl = isQ ? QSCALE : 1.0f;
            unsigned short* dst = isQ ? qo : ko;
            const int c = nn >> 4, h8 = (nn >> 3) & 1, jj = nn & 7;
            #pragma unroll
            for (int mf = 0; mf < 4; ++mf) {
                const int m = m0 + wm * 64 + mf * 16 + lg * 4;
                const int b_ = m >> 12;
                const int T = (m & 4095) >> 5;
                const size_t base =
                    ((((size_t)b_ * 128 + T) * 4 + c) * 64) * 8 + jj;
                #pragma unroll
                for (int r = 0; r < 4; ++r) {
                    const int l = (((m + r) & 31) + 32 * h8);
                    dst[base + (size_t)l * 8] = f2bf((acc[mf][nf][r] + bias) * scl);
                }
            }
        } else {
            const int o = n - 128;
            const float bias = bv[o];
            const int og = o >> 6;
            const int fo = (o >> 5) & 1;
            #pragma unroll
            for (int mf = 0; mf < 4; ++mf) {
                const int m = m0 + wm * 64 + mf * 16 + lg * 4;   // token of r=0
                const int b_ = m >> 12;
                const int tl = m & 4095;
                const int T = tl >> 5;
                const int kk = tl & 31;
                const int f = fo * 2 + ((kk >> 4) & 1);
                const int h8 = (kk >> 3) & 1;
                const int jb = kk & 7;                            // 0 or 4
                const int l = (o & 31) + 32 * h8;
                const size_t addr =
                    (((((size_t)b_ * 128 + T) * 8 + og) * 4 + f) * 64 + l) * 8 + jb;
                ushort4 p;
                p.x = f2bf(acc[mf][nf][0] + bias);
                p.y = f2bf(acc[mf][nf][1] + bias);
                p.z = f2bf(acc[mf][nf][2] + bias);
                p.w = f2bf(acc[mf][nf][3] + bias);
                *(ushort4*)&vt[addr] = p;
            }
        }
    }
}

// ---------------- Kernel 2: LDS-free flash attention, K-parity split -------
// 512 blocks x 256 thr = 2048 waves (2/SIMD). Wave = (batch, jp, og4, parity):
// processes k-steps of its parity for tile jp then tile 127-jp (64/65 steps
// every wave). Constant-shift softmax => parity partials combine by addition
// (LDS exchange within block). All loads coalesced from fragment-tiled ws.
__global__ __launch_bounds__(256, 2) void attn_mfma(
    const unsigned short* __restrict__ qtb,
    const unsigned short* __restrict__ ktb,
    const unsigned short* __restrict__ vtt,
    float* __restrict__ out)
{
    __shared__ float xch[2][64][65];   // [task slot][lane][64 acc + 1 l]

    const int tid  = threadIdx.x;
    const int wid  = tid >> 6;
    const int lane = tid & 63;
    const int m31  = lane & 31;
    const int hi   = lane >> 5;
    const int bid  = blockIdx.x;

    // decode: bid = jp*8 + x ; x = XCD id (round-robin assumption, perf-only)
    const int jp  = bid >> 3;         // 0..63
    const int x   = bid & 7;
    const int b   = x >> 1;           // batch pinned to XCD pair
    const int y   = x & 1;
    const int og4 = y * 2 + (wid >> 1);   // 0..3 (128 out-cols each)
    const int par = wid & 1;              // K parity
    const int slot = wid >> 1;

    const unsigned short* Qb = qtb + (size_t)b * 128 * 2048;
    const unsigned short* Kb = ktb + (size_t)b * 128 * 2048;
    const unsigned short* Vb = vtt + (size_t)b * 128 * 16384;
    float* outb = out + (size_t)b * LL * OUTC;

    #pragma unroll 1
    for (int ph = 0; ph < 2; ++ph) {
        const int T  = ph ? (127 - jp) : jp;
        const int q0 = T * 32;

        // Q fragments (coalesced 1KB loads)
        short8 qf[4];
        {
            const unsigned short* p = Qb + (size_t)T * 2048 + lane * 8;
            #pragma unroll
            for (int c = 0; c < 4; ++c) qf[c] = *(const short8*)(p + c * 512);
        }

        f32x16 ac0, ac1, ac2, ac3;
        #pragma unroll
        for (int i = 0; i < 16; ++i) { ac0[i]=0.f; ac1[i]=0.f; ac2[i]=0.f; ac3[i]=0.f; }
        float ls = 0.f;

        short8 kfA[4], kfB[4], vf[8];

        auto LOADK = [&](int t, short8 (&KF)[4]) {
            const unsigned short* p = Kb + (size_t)t * 2048 + lane * 8;
            KF[0] = *(const short8*)(p);
            KF[1] = *(const short8*)(p + 512);
            KF[2] = *(const short8*)(p + 1024);
            KF[3] = *(const short8*)(p + 1536);
        };
        auto LOADV = [&](int t) {
            const unsigned short* p0 = Vb + (size_t)t * 16384 + (og4 * 2) * 2048 + lane * 8;
            #pragma unroll
            for (int f = 0; f < 4; ++f) vf[f] = *(const short8*)(p0 + f * 512);
            const unsigned short* p1 = p0 + 2048;
            #pragma unroll
            for (int f = 0; f < 4; ++f) vf[4 + f] = *(const short8*)(p1 + f * 512);
        };

        auto STEP = [&](bool diag, const short8 (&KF)[4]) {
            f32x16 s;
            #pragma unroll
            for (int i = 0; i < 16; ++i) s[i] = 0.f;
            __builtin_amdgcn_s_setprio(1);
            #pragma unroll
            for (int c = 0; c < 4; ++c)
                s = __builtin_amdgcn_mfma_f32_32x32x16_bf16(KF[c], qf[c], s, 0, 0, 0);
            __builtin_amdgcn_s_setprio(0);
            if (diag) {
                #pragma unroll
                for (int jj = 0; jj < 16; ++jj) {
                    const int pos = (jj & 3) + 8 * (jj >> 2) + 4 * hi;
                    if (pos > m31) s[jj] = -30000.f;
                }
            }
            float p[16];
            #pragma unroll
            for (int jj = 0; jj < 16; ++jj) p[jj] = EXP2(s[jj] - MSHIFT);
            {
                float t0 = (p[0] + p[1]) + (p[2] + p[3]);
                float t1 = (p[4] + p[5]) + (p[6] + p[7]);
                float t2 = (p[8] + p[9]) + (p[10] + p[11]);
                float t3 = (p[12] + p[13]) + (p[14] + p[15]);
                ls += (t0 + t1) + (t2 + t3);
            }
            unsigned a0, a1, b0, b1, a2, a3, b2, b3;
            asm("v_cvt_pk_bf16_f32 %0, %1, %2" : "=v"(a0) : "v"(p[0]),  "v"(p[1]));
            asm("v_cvt_pk_bf16_f32 %0, %1, %2" : "=v"(a1) : "v"(p[2]),  "v"(p[3]));
            asm("v_cvt_pk_bf16_f32 %0, %1, %2" : "=v"(b0) : "v"(p[4]),  "v"(p[5]));
            asm("v_cvt_pk_bf16_f32 %0, %1, %2" : "=v"(b1) : "v"(p[6]),  "v"(p[7]));
            asm("v_cvt_pk_bf16_f32 %0, %1, %2" : "=v"(a2) : "v"(p[8]),  "v"(p[9]));
            asm("v_cvt_pk_bf16_f32 %0, %1, %2" : "=v"(a3) : "v"(p[10]), "v"(p[11]));
            asm("v_cvt_pk_bf16_f32 %0, %1, %2" : "=v"(b2) : "v"(p[12]), "v"(p[13]));
            asm("v_cvt_pk_bf16_f32 %0, %1, %2" : "=v"(b3) : "v"(p[14]), "v"(p[15]));
            auto r0 = __builtin_amdgcn_permlane32_swap(a0, b0, false, false);
            auto r1 = __builtin_amdgcn_permlane32_swap(a1, b1, false, false);
            auto r2 = __builtin_amdgcn_permlane32_swap(a2, b2, false, false);
            auto r3 = __builtin_amdgcn_permlane32_swap(a3, b3, false, false);
            union { unsigned u[4]; short8 s8; } pf0, pf1;
            pf0.u[0] = r0[0]; pf0.u[1] = r1[0]; pf0.u[2] = r0[1]; pf0.u[3] = r1[1];
            pf1.u[0] = r2[0]; pf1.u[1] = r3[0]; pf1.u[2] = r2[1]; pf1.u[3] = r3[1];

            __builtin_amdgcn_s_setprio(1);
            ac0 = __builtin_amdgcn_mfma_f32_32x32x16_bf16(vf[0], pf0.s8, ac0, 0, 0, 0);
            ac0 = __builtin_amdgcn_mfma_f32_32x32x16_bf16(vf[1], pf1.s8, ac0, 0, 0, 0);
            ac1 = __builtin_amdgcn_mfma_f32_32x32x16_bf16(vf[2], pf0.s8, ac1, 0, 0, 0);
            ac1 = __builtin_amdgcn_mfma_f32_32x32x16_bf16(vf[3], pf1.s8, ac1, 0, 0, 0);
            ac2 = __builtin_amdgcn_mfma_f32_32x32x16_bf16(vf[4], pf0.s8, ac2, 0, 0, 0);
            ac2 = __builtin_amdgcn_mfma_f32_32x32x16_bf16(vf[5], pf1.s8, ac2, 0, 0, 0);
            ac3 = __builtin_amdgcn_mfma_f32_32x32x16_bf16(vf[6], pf0.s8, ac3, 0, 0, 0);
            ac3 = __builtin_amdgcn_mfma_f32_32x32x16_bf16(vf[7], pf1.s8, ac3, 0, 0, 0);
            __builtin_amdgcn_s_setprio(0);
        };

        int t = par;
        if (t <= T) {
            LOADK(t, kfA);
            for (;;) {
                LOADV(t);
                if (t + 2 <= T) LOADK(t + 2, kfB);
                STEP(t == T, kfA);
                t += 2; if (t > T) break;
                LOADV(t);
                if (t + 2 <= T) LOADK(t + 2, kfA);
                STEP(t == T, kfB);
                t += 2; if (t > T) break;
            }
        }
        ls = pswap_sum(ls);

        __syncthreads();
        if (par) {
            float* dst = &xch[slot][lane][0];
            #pragma unroll
            for (int i = 0; i < 16; ++i) dst[i]      = ac0[i];
            #pragma unroll
            for (int i = 0; i < 16; ++i) dst[16 + i] = ac1[i];
            #pragma unroll
            for (int i = 0; i < 16; ++i) dst[32 + i] = ac2[i];
            #pragma unroll
            for (int i = 0; i < 16; ++i) dst[48 + i] = ac3[i];
            dst[64] = ls;
        }
        __syncthreads();
        if (!par) {
            const float* src = &xch[slot][lane][0];
            const float inv = 1.f / (ls + src[64]);
            float* row = outb + (size_t)(q0 + m31) * OUTC + og4 * 128 + hi * 4;
            #pragma unroll
            for (int g = 0; g < 4; ++g) {
                float4 w;
                w.x = (ac0[g*4+0] + src[g*4+0]) * inv;
                w.y = (ac0[g*4+1] + src[g*4+1]) * inv;
                w.z = (ac0[g*4+2] + src[g*4+2]) * inv;
                w.w = (ac0[g*4+3] + src[g*4+3]) * inv;
                *(float4*)(row + g * 8) = w;
                w.x = (ac1[g*4+0] + src[16+g*4+0]) * inv;
                w.y = (ac1[g*4+1] + src[16+g*4+1]) * inv;
                w.z = (ac1[g*4+2] + src[16+g*4+2]) * inv;
                w.w = (ac1[g*4+3] + src[16+g*4+3]) * inv;
                *(float4*)(row + 32 + g * 8) = w;
                w.x = (ac2[g*4+0] + src[32+g*4+0]) * inv;
                w.y = (ac2[g*4+1] + src[32+g*4+1]) * inv;
                w.z = (ac2[g*4+2] + src[32+g*4+2]) * inv;
                w.w = (ac2[g*4+3] + src[32+g*4+3]) * inv;
                *(float4*)(row + 64 + g * 8) = w;
                w.x = (ac3[g*4+0] + src[48+g*4+0]) * inv;
                w.y = (ac3[g*4+1] + src[48+g*4+1]) * inv;
                w.z = (ac3[g*4+2] + src[48+g*4+2]) * inv;
                w.w = (ac3[g*4+3] + src[48+g*4+3]) * inv;
                *(float4*)(row + 96 + g * 8) = w;
            }
        }
    }
}

extern "C" void kernel_launch(void* const* d_in, const int* in_sizes, int n_in,
                              void* d_out, int out_size, void* d_ws, size_t ws_size,
                              hipStream_t stream) {
    const float* x  = (const float*)d_in[0];
    const float* Wq = (const float*)d_in[1];
    const float* bq = (const float*)d_in[2];
    const float* Wk = (const float*)d_in[3];
    const float* bk = (const float*)d_in[4];
    const float* Wv = (const float*)d_in[5];
    const float* bv = (const float*)d_in[6];
    float* out = (float*)d_out;

    unsigned short* xb  = (unsigned short*)d_ws;
    unsigned short* wb  = xb + (size_t)MTOT * CC;
    unsigned short* qbf = wb + (size_t)NTOT * CC;
    unsigned short* kbf = qbf + (size_t)MTOT * DKK;
    unsigned short* vtb = kbf + (size_t)MTOT * DKK;

    const int total4 = (MTOT * CC + NTOT * CC) / 4;
    cvt_inputs<<<(total4 + 255) / 256, 256, 0, stream>>>(x, Wq, Wk, Wv, xb, wb);

    dim3 gG(MTOT / 128, NTOT / 128);
    proj_gemm<<<gG, 256, 0, stream>>>(xb, wb, bq, bk, bv, qbf, kbf, vtb);

    attn_mfma<<<512, 256, 0, stream>>>(qbf, kbf, vtb, out);
}